// Round 6
// baseline (343.011 us; speedup 1.0000x reference)
//
#include <hip/hip_runtime.h>
#include <hip/hip_cooperative_groups.h>
#include <hip/hip_bf16.h>

namespace cg = cooperative_groups;

#define N_POS 9216
#define NCHUNK 9
#define BATCH 8
#define CDIM 64
#define HEADS 4
#define EPS 1e-5f

// ws layout: stats fp32(128) | Pparts fp32 (72 chunks x 16 partials x 4096) |
//            Mp fp32 4x(72*4096) | ybf bf16
#define NPART 16
#define PPARTS_TOT ((size_t)BATCH * NCHUNK * NPART * 4096)
#define MP_SLICE ((size_t)(BATCH * NCHUNK) * 4096)   // floats per head-partial of M

typedef __attribute__((ext_vector_type(8))) short short8;
typedef __attribute__((ext_vector_type(4))) float f32x4;

static __device__ inline unsigned pk2(float a, float b) {
    __hip_bfloat162 h2(__float2bfloat16(a), __float2bfloat16(b));
    return *reinterpret_cast<unsigned*>(&h2);
}
static __device__ inline float bf2f(short s) {
    union { unsigned u; float f; } c; c.u = ((unsigned)(unsigned short)s) << 16; return c.f;
}
static __device__ inline short8 mk8(unsigned a, unsigned b, unsigned c, unsigned d) {
    union { short8 s; unsigned u[4]; } cv;
    cv.u[0] = a; cv.u[1] = b; cv.u[2] = c; cv.u[3] = d; return cv.s;
}

// ---------------- Phase A: q,k + P partials (R4-verified register pipeline) ---
// task in [0,1152): bx = task%144 (9 ck x 16 pt), b = task/144.
static __device__ __forceinline__ void phaseA_task(int task, int t,
        const float* __restrict__ x, const float* __restrict__ Wqkv,
        float* __restrict__ Pparts) {
    __shared__ __align__(16) __hip_bfloat16 xs[64][72];   // 9.2 KB
    int w = t >> 6, l = t & 63;
    int l15 = l & 15, quad = l >> 4;
    int bx = task % 144, b = task / 144;
    int ck = bx >> 4, pt = bx & 15;
    int n0 = bx * 64;
    __syncthreads();   // protect xs reuse across task iterations
    {
        int p = t & 63, cbase = (t >> 6) * 16;
        const float* xb = x + (size_t)b * CDIM * N_POS + n0 + p;
        #pragma unroll
        for (int j = 0; j < 16; j += 4) {
            float v0 = xb[(size_t)(cbase + j + 0) * N_POS];
            float v1 = xb[(size_t)(cbase + j + 1) * N_POS];
            float v2 = xb[(size_t)(cbase + j + 2) * N_POS];
            float v3 = xb[(size_t)(cbase + j + 3) * N_POS];
            uint2 u; u.x = pk2(v0, v1); u.y = pk2(v2, v3);
            *reinterpret_cast<uint2*>(&xs[p][cbase + j]) = u;
        }
    }
    __syncthreads();

    // qk MFMA: nt 0,1 = q-ch of head w, nt 2,3 = k-ch of head w; W cvt in-register
    f32x4 acc[4][4];
    #pragma unroll
    for (int mt = 0; mt < 4; ++mt)
        #pragma unroll
        for (int nt = 0; nt < 4; ++nt) acc[mt][nt] = (f32x4){0.f, 0.f, 0.f, 0.f};
    #pragma unroll
    for (int ks = 0; ks < 2; ++ks) {
        int k0 = ks * 32 + quad * 8;
        short8 av[4];
        #pragma unroll
        for (int mt = 0; mt < 4; ++mt)
            av[mt] = *reinterpret_cast<const short8*>(&xs[mt * 16 + l15][k0]);
        #pragma unroll
        for (int nt = 0; nt < 4; ++nt) {
            int row = (nt < 2) ? (w * 32 + nt * 16 + l15)
                               : (128 + w * 32 + (nt - 2) * 16 + l15);
            const float4* wr = (const float4*)(Wqkv + (size_t)row * 64 + k0);
            float4 wa = wr[0], wb = wr[1];
            short8 bwv = mk8(pk2(wa.x, wa.y), pk2(wa.z, wa.w),
                             pk2(wb.x, wb.y), pk2(wb.z, wb.w));
            #pragma unroll
            for (int mt = 0; mt < 4; ++mt)
                acc[mt][nt] = __builtin_amdgcn_mfma_f32_16x16x32_bf16(av[mt], bwv, acc[mt][nt], 0, 0, 0);
        }
    }

    // softmax/exp in-register, pack to bf16 pairs
    unsigned pk[4][4][2];
    #pragma unroll
    for (int mt = 0; mt < 4; ++mt) {
        f32x4 e2, e3;
        #pragma unroll
        for (int r = 0; r < 4; ++r) {
            float a2 = acc[mt][2][r], a3 = acc[mt][3][r];
            float m = fmaxf(a2, a3);
            m = fmaxf(m, __shfl_xor(m, 1));
            m = fmaxf(m, __shfl_xor(m, 2));
            m = fmaxf(m, __shfl_xor(m, 4));
            m = fmaxf(m, __shfl_xor(m, 8));
            float x2 = __expf(a2 - m), x3 = __expf(a3 - m);
            float s = x2 + x3;
            s += __shfl_xor(s, 1);
            s += __shfl_xor(s, 2);
            s += __shfl_xor(s, 4);
            s += __shfl_xor(s, 8);
            float is = 1.f / s;
            e2[r] = x2 * is; e3[r] = x3 * is;
        }
        pk[mt][2][0] = pk2(e2[0], e2[1]); pk[mt][2][1] = pk2(e2[2], e2[3]);
        pk[mt][3][0] = pk2(e3[0], e3[1]); pk[mt][3][1] = pk2(e3[2], e3[3]);
        pk[mt][0][0] = pk2(__expf(acc[mt][0][0]), __expf(acc[mt][0][1]));
        pk[mt][0][1] = pk2(__expf(acc[mt][0][2]), __expf(acc[mt][0][3]));
        pk[mt][1][0] = pk2(__expf(acc[mt][1][0]), __expf(acc[mt][1][1]));
        pk[mt][1][1] = pk2(__expf(acc[mt][1][2]), __expf(acc[mt][1][3]));
    }

    // shuffle-transpose to P-fragments + P MFMA
    f32x4 pac[2][2];
    pac[0][0] = (f32x4){0,0,0,0}; pac[0][1] = (f32x4){0,0,0,0};
    pac[1][0] = (f32x4){0,0,0,0}; pac[1][1] = (f32x4){0,0,0,0};
    int srcbase = ((quad & 1) * 2) * 16 + l15;
    bool hiHalf = (quad >= 2);
    #pragma unroll
    for (int ks = 0; ks < 2; ++ks) {
        unsigned fr[4][4];
        #pragma unroll
        for (int nt = 0; nt < 4; ++nt) {
            #pragma unroll
            for (int sl = 0; sl < 4; ++sl) {
                int src = srcbase + (sl >> 1) * 16;
                unsigned lo = __shfl(pk[2 * ks][nt][sl & 1], src);
                unsigned hi = __shfl(pk[2 * ks + 1][nt][sl & 1], src);
                fr[nt][sl] = hiHalf ? hi : lo;
            }
        }
        short8 A0 = mk8(fr[0][0], fr[0][1], fr[0][2], fr[0][3]);
        short8 A1 = mk8(fr[1][0], fr[1][1], fr[1][2], fr[1][3]);
        short8 B0 = mk8(fr[2][0], fr[2][1], fr[2][2], fr[2][3]);
        short8 B1 = mk8(fr[3][0], fr[3][1], fr[3][2], fr[3][3]);
        pac[0][0] = __builtin_amdgcn_mfma_f32_16x16x32_bf16(A0, B0, pac[0][0], 0, 0, 0);
        pac[0][1] = __builtin_amdgcn_mfma_f32_16x16x32_bf16(A0, B1, pac[0][1], 0, 0, 0);
        pac[1][0] = __builtin_amdgcn_mfma_f32_16x16x32_bf16(A1, B0, pac[1][0], 0, 0, 0);
        pac[1][1] = __builtin_amdgcn_mfma_f32_16x16x32_bf16(A1, B1, pac[1][1], 0, 0, 0);
    }
    float* Pp = Pparts + (((size_t)(b * NCHUNK + ck) * NPART + pt) * 4 + w) * 1024;
    #pragma unroll
    for (int tA = 0; tA < 2; ++tA)
        #pragma unroll
        for (int tB = 0; tB < 2; ++tB)
            #pragma unroll
            for (int r = 0; r < 4; ++r)
                Pp[(tA * 16 + quad * 4 + r) * 32 + tB * 16 + l15] = pac[tA][tB][r];
}

// ---------------- Phase B: P -> M head-partials -------------------------------
// task in [0,288): ck = task%9, r2 = task/9, b = r2&7, h = r2>>3.
static __device__ __forceinline__ void phaseB_task(int task, int t,
        const float* __restrict__ Wqkv, const float* __restrict__ Wout,
        const float* __restrict__ Pparts, float* __restrict__ Mp) {
    __shared__ float Pl[32][32];
    __shared__ float iZ[32];
    __shared__ float Ul[64][33];
    __shared__ float Wvh[32][68];
    int ck = task % 9; int r2 = task / 9; int b = r2 & 7; int h = r2 >> 3;
    __syncthreads();   // protect Wvh/Ul reuse across task iterations
    {
        const float4* P0 = (const float4*)Pparts
            + ((size_t)(b * NCHUNK + ck) * NPART) * 1024 + h * 256 + t;
        float4 s = (float4){0.f, 0.f, 0.f, 0.f};
        #pragma unroll
        for (int pt = 0; pt < NPART; ++pt) {
            float4 a = P0[pt * 1024];
            s.x += a.x; s.y += a.y; s.z += a.z; s.w += a.w;
        }
        ((float4*)Pl)[t] = s;
    }
    {   // stage Wv_h
        int e = t >> 3, cq = t & 7;
        const float4* wr = (const float4*)(Wqkv + (size_t)(256 + h * 32 + e) * 64 + cq * 8);
        float4 a0 = wr[0], a1 = wr[1];
        *reinterpret_cast<float4*>(&Wvh[e][cq * 8])     = a0;
        *reinterpret_cast<float4*>(&Wvh[e][cq * 8 + 4]) = a1;
    }
    __syncthreads();
    if (t < 32) {
        float s = 0.f;
        #pragma unroll
        for (int c = 0; c < 32; ++c) s += Pl[t][c];
        iZ[t] = 1.f / s;
    }
    __syncthreads();
    int o = t & 63, wv = t >> 6;
    float wz[32];
    {
        const float4* wr = (const float4*)(Wout + (size_t)o * 128 + h * 32);
        #pragma unroll
        for (int j = 0; j < 8; ++j) {
            float4 f = wr[j];
            wz[j*4+0] = f.x * iZ[j*4+0]; wz[j*4+1] = f.y * iZ[j*4+1];
            wz[j*4+2] = f.z * iZ[j*4+2]; wz[j*4+3] = f.w * iZ[j*4+3];
        }
    }
    float ua[8];
    #pragma unroll
    for (int j = 0; j < 8; ++j) ua[j] = 0.f;
    for (int d = 0; d < 32; ++d) {
        float wd = wz[d];
        #pragma unroll
        for (int j = 0; j < 8; ++j) ua[j] += wd * Pl[d][wv * 8 + j];
    }
    #pragma unroll
    for (int j = 0; j < 8; ++j) Ul[o][wv * 8 + j] = ua[j];
    __syncthreads();

    float macc[16];
    #pragma unroll
    for (int j = 0; j < 16; ++j) macc[j] = 0.f;
    for (int e = 0; e < 32; ++e) {
        float u = Ul[o][e];
        const float4* wvp = reinterpret_cast<const float4*>(&Wvh[e][wv * 16]);
        #pragma unroll
        for (int q = 0; q < 4; ++q) {
            float4 f = wvp[q];
            macc[q*4+0] += u * f.x; macc[q*4+1] += u * f.y;
            macc[q*4+2] += u * f.z; macc[q*4+3] += u * f.w;
        }
    }
    float* mp = Mp + (size_t)h * MP_SLICE + ((size_t)(b * NCHUNK + ck)) * 4096
              + (size_t)o * 64 + wv * 16;
    #pragma unroll
    for (int q = 0; q < 4; ++q) {
        float4 f; f.x = macc[q*4+0]; f.y = macc[q*4+1]; f.z = macc[q*4+2]; f.w = macc[q*4+3];
        reinterpret_cast<float4*>(mp)[q] = f;
    }
}

// ---------------- Phase C: y = M.x + bias, GN stats ---------------------------
// task in [0,576): bx = task%72, b = task/72.
static __device__ __forceinline__ void phaseC_task(int task, int t,
        const float* __restrict__ x, const float* __restrict__ Mp,
        const float* __restrict__ bout, __hip_bfloat16* __restrict__ ybf,
        float* __restrict__ stats) {
    __shared__ __align__(16) __hip_bfloat16 xs[128][72];   // 18.4 KB
    __shared__ __align__(16) __hip_bfloat16 Ml[64][72];    // 9.2 KB
    __shared__ float gsum[8], gsq[8];
    int w = t >> 6, l = t & 63;
    int l15 = l & 15, quad = l >> 4;
    int bx = task % 72, b = task / 72;
    int ck = bx >> 3;
    int n0 = bx * 128;
    __syncthreads();   // protect xs/Ml reuse across task iterations
    if (t < 8) { gsum[t] = 0.f; gsq[t] = 0.f; }
    {   // stage x tile: 2 threads per position, 32 channels each
        int p = t & 127, cbase = (t >> 7) * 32;
        const float* xb = x + (size_t)b * CDIM * N_POS + n0 + p;
        #pragma unroll
        for (int j = 0; j < 32; j += 4) {
            float v0 = xb[(size_t)(cbase + j + 0) * N_POS];
            float v1 = xb[(size_t)(cbase + j + 1) * N_POS];
            float v2 = xb[(size_t)(cbase + j + 2) * N_POS];
            float v3 = xb[(size_t)(cbase + j + 3) * N_POS];
            uint2 u; u.x = pk2(v0, v1); u.y = pk2(v2, v3);
            *reinterpret_cast<uint2*>(&xs[p][cbase + j]) = u;
        }
    }
    {   // stage M: sum 4 head-partials (L2-hot), cvt to bf16
        int o = t >> 2, cs = (t & 3) * 16;
        const float* mb = Mp + ((size_t)(b * NCHUNK + ck)) * 4096 + (size_t)o * 64 + cs;
        float m[16];
        #pragma unroll
        for (int q = 0; q < 4; ++q) {
            float4 f = reinterpret_cast<const float4*>(mb)[q];
            m[q*4+0] = f.x; m[q*4+1] = f.y; m[q*4+2] = f.z; m[q*4+3] = f.w;
        }
        #pragma unroll
        for (int h = 1; h < 4; ++h) {
            const float* mh = mb + h * MP_SLICE;
            #pragma unroll
            for (int q = 0; q < 4; ++q) {
                float4 f = reinterpret_cast<const float4*>(mh)[q];
                m[q*4+0] += f.x; m[q*4+1] += f.y; m[q*4+2] += f.z; m[q*4+3] += f.w;
            }
        }
        #pragma unroll
        for (int q = 0; q < 4; ++q) {
            uint2 u; u.x = pk2(m[q*4+0], m[q*4+1]); u.y = pk2(m[q*4+2], m[q*4+3]);
            *reinterpret_cast<uint2*>(&Ml[o][cs + q * 4]) = u;
        }
    }
    __syncthreads();

    int nw = w * 32;
    f32x4 acc[4][2];
    #pragma unroll
    for (int mt = 0; mt < 4; ++mt) { acc[mt][0] = (f32x4){0,0,0,0}; acc[mt][1] = (f32x4){0,0,0,0}; }
    #pragma unroll
    for (int ks = 0; ks < 2; ++ks) {
        int k0 = ks * 32 + quad * 8;
        short8 bf[2];
        #pragma unroll
        for (int nt = 0; nt < 2; ++nt)
            bf[nt] = *reinterpret_cast<const short8*>(&xs[nw + nt * 16 + l15][k0]);
        #pragma unroll
        for (int mt = 0; mt < 4; ++mt) {
            short8 af = *reinterpret_cast<const short8*>(&Ml[mt * 16 + l15][k0]);
            acc[mt][0] = __builtin_amdgcn_mfma_f32_16x16x32_bf16(af, bf[0], acc[mt][0], 0, 0, 0);
            acc[mt][1] = __builtin_amdgcn_mfma_f32_16x16x32_bf16(af, bf[1], acc[mt][1], 0, 0, 0);
        }
    }
    float gsl[4], gql[4];
    #pragma unroll
    for (int mt = 0; mt < 4; ++mt) { gsl[mt] = 0.f; gql[mt] = 0.f; }
    __hip_bfloat16* yb = ybf + (size_t)b * CDIM * N_POS;
    int nbase = n0 + nw;
    #pragma unroll
    for (int mt = 0; mt < 4; ++mt) {
        float4 bo = *reinterpret_cast<const float4*>(bout + mt * 16 + quad * 4);
        const float* bop = reinterpret_cast<const float*>(&bo);
        #pragma unroll
        for (int nt = 0; nt < 2; ++nt) {
            int n = nbase + nt * 16 + l15;
            #pragma unroll
            for (int r = 0; r < 4; ++r) {
                int o = mt * 16 + quad * 4 + r;
                float val = acc[mt][nt][r] + bop[r];
                yb[(size_t)o * N_POS + n] = __float2bfloat16(val);
                gsl[mt] += val; gql[mt] += val * val;
            }
        }
    }
    #pragma unroll
    for (int off = 16; off >= 1; off >>= 1) {
        #pragma unroll
        for (int mt = 0; mt < 4; ++mt) {
            gsl[mt] += __shfl_xor(gsl[mt], off, 64);
            gql[mt] += __shfl_xor(gql[mt], off, 64);
        }
    }
    if (l == 0 || l == 32) {
        int qh = quad >> 1;
        #pragma unroll
        for (int mt = 0; mt < 4; ++mt) {
            atomicAdd(&gsum[2 * mt + qh], gsl[mt]);
            atomicAdd(&gsq[2 * mt + qh], gql[mt]);
        }
    }
    __syncthreads();
    if (t < 8) {
        atomicAdd(&stats[(b * 8 + t) * 2],     gsum[t]);
        atomicAdd(&stats[(b * 8 + t) * 2 + 1], gsq[t]);
    }
}

// ---------------- Phase D: GroupNorm apply ------------------------------------
// task in [0,4608): bx9 = task%9, bc = task/9 (= b*64+c).
static __device__ __forceinline__ void phaseD_task(int task, int t,
        const __hip_bfloat16* __restrict__ ybf, const float* __restrict__ stats,
        const float* __restrict__ gamma, const float* __restrict__ beta,
        float* __restrict__ out) {
    int bx9 = task % 9; int bc = task / 9;
    int c = bc & 63, b = bc >> 6;
    int g = c >> 3;
    float s = stats[(b * 8 + g) * 2], q = stats[(b * 8 + g) * 2 + 1];
    const float invN = 1.f / (8.f * N_POS);
    float mean = s * invN;
    float var = q * invN - mean * mean;
    float sc = rsqrtf(var + EPS);
    float ga = gamma[c] * sc;
    float be = beta[c] - mean * sc * gamma[c];
    size_t base = ((size_t)b * CDIM + c) * N_POS + (size_t)(bx9 * 256 + t) * 4;
    uint2 u = *reinterpret_cast<const uint2*>(ybf + base);
    float4 v;
    v.x = bf2f((short)(u.x & 0xffff)); v.y = bf2f((short)(u.x >> 16));
    v.z = bf2f((short)(u.y & 0xffff)); v.w = bf2f((short)(u.y >> 16));
    v.x = v.x * ga + be; v.y = v.y * ga + be; v.z = v.z * ga + be; v.w = v.w * ga + be;
    *reinterpret_cast<float4*>(out + base) = v;
}

// ---------------- Fused cooperative kernel ------------------------------------
__global__ __launch_bounds__(256, 2) void fused_kernel(
        const float* __restrict__ x, const float* __restrict__ Wqkv,
        const float* __restrict__ Wout, const float* __restrict__ bout,
        const float* __restrict__ gamma, const float* __restrict__ beta,
        float* __restrict__ out, float* __restrict__ stats,
        float* __restrict__ Pparts, float* __restrict__ Mp,
        __hip_bfloat16* __restrict__ ybf) {
    cg::grid_group gg = cg::this_grid();
    int t = threadIdx.x;
    if (blockIdx.x == 0 && t < 128) stats[t] = 0.f;
    for (int task = blockIdx.x; task < 1152; task += gridDim.x)
        phaseA_task(task, t, x, Wqkv, Pparts);
    __threadfence();
    gg.sync();
    for (int task = blockIdx.x; task < 288; task += gridDim.x)
        phaseB_task(task, t, Wqkv, Wout, Pparts, Mp);
    __threadfence();
    gg.sync();
    for (int task = blockIdx.x; task < 576; task += gridDim.x)
        phaseC_task(task, t, x, Mp, bout, ybf, stats);
    __threadfence();
    gg.sync();
    for (int task = blockIdx.x; task < 4608; task += gridDim.x)
        phaseD_task(task, t, ybf, stats, gamma, beta, out);
}

// ---------------- Fallback plain kernels (used if coop launch unavailable) ----
__global__ __launch_bounds__(256) void kA(const float* __restrict__ x,
        const float* __restrict__ Wqkv, float* __restrict__ Pparts,
        float* __restrict__ stats) {
    if (blockIdx.x == 0 && threadIdx.x < 128) stats[threadIdx.x] = 0.f;
    phaseA_task(blockIdx.x, threadIdx.x, x, Wqkv, Pparts);
}
__global__ __launch_bounds__(256) void kB(const float* __restrict__ Wqkv,
        const float* __restrict__ Wout, const float* __restrict__ Pparts,
        float* __restrict__ Mp) {
    phaseB_task(blockIdx.x, threadIdx.x, Wqkv, Wout, Pparts, Mp);
}
__global__ __launch_bounds__(256) void kC(const float* __restrict__ x,
        const float* __restrict__ Mp, const float* __restrict__ bout,
        __hip_bfloat16* __restrict__ ybf, float* __restrict__ stats) {
    phaseC_task(blockIdx.x, threadIdx.x, x, Mp, bout, ybf, stats);
}
__global__ __launch_bounds__(256) void kD(const __hip_bfloat16* __restrict__ ybf,
        const float* __restrict__ stats, const float* __restrict__ gamma,
        const float* __restrict__ beta, float* __restrict__ out) {
    phaseD_task(blockIdx.x, threadIdx.x, ybf, stats, gamma, beta, out);
}

extern "C" void kernel_launch(void* const* d_in, const int* in_sizes, int n_in,
                              void* d_out, int out_size, void* d_ws, size_t ws_size,
                              hipStream_t stream) {
    const float* x     = (const float*)d_in[0];
    const float* Wqkv  = (const float*)d_in[1];
    const float* Wout  = (const float*)d_in[2];
    const float* bout  = (const float*)d_in[3];
    const float* gamma = (const float*)d_in[4];
    const float* beta  = (const float*)d_in[5];
    float* out = (float*)d_out;

    float* stats  = (float*)d_ws;
    float* Pparts = stats + 128;
    float* Mp     = Pparts + PPARTS_TOT;
    __hip_bfloat16* ybf = (__hip_bfloat16*)(Mp + 4 * MP_SLICE);

    // Decide cooperative grid size once (host-side query; no stream ops).
    static int coopBlocks = -1;
    if (coopBlocks < 0) {
        int nb = 0;
        if (hipOccupancyMaxActiveBlocksPerMultiprocessor(
                &nb, (const void*)fused_kernel, 256, 0) != hipSuccess || nb < 1)
            nb = 0;
        coopBlocks = nb * 256;            // 256 CUs on MI355X
        if (coopBlocks > 512) coopBlocks = 512;
    }

    bool done = false;
    if (coopBlocks >= 256) {
        void* args[] = { (void*)&x, (void*)&Wqkv, (void*)&Wout, (void*)&bout,
                         (void*)&gamma, (void*)&beta, (void*)&out, (void*)&stats,
                         (void*)&Pparts, (void*)&Mp, (void*)&ybf };
        if (hipLaunchCooperativeKernel((const void*)fused_kernel,
                dim3(coopBlocks), dim3(256), args, 0, stream) == hipSuccess)
            done = true;
    }
    if (!done) {
        kA<<<dim3(1152), 256, 0, stream>>>(x, Wqkv, Pparts, stats);
        kB<<<dim3(288),  256, 0, stream>>>(Wqkv, Wout, Pparts, Mp);
        kC<<<dim3(576),  256, 0, stream>>>(x, Mp, bout, ybf, stats);
        kD<<<dim3(4608), 256, 0, stream>>>(ybf, stats, gamma, beta, out);
    }
}

// Round 7
// 238.785 us; speedup vs baseline: 1.4365x; 1.4365x over previous
//
#include <hip/hip_runtime.h>
#include <hip/hip_bf16.h>

#define N_POS 9216
#define NCHUNK 9
#define BATCH 8
#define CDIM 64
#define HEADS 4
#define EPS 1e-5f

// ws layout: stats f32[128] | cntY u32[8] | pad to 1024B | Pparts fp32 | Mp fp32 (4 head-slices)
#define NPART 16
#define PPARTS_TOT ((size_t)BATCH * NCHUNK * NPART * 4096)
#define MP_SLICE ((size_t)(BATCH * NCHUNK) * 4096)

typedef __attribute__((ext_vector_type(8))) short short8;
typedef __attribute__((ext_vector_type(4))) float f32x4;

static __device__ inline unsigned pk2(float a, float b) {
    __hip_bfloat162 h2(__float2bfloat16(a), __float2bfloat16(b));
    return *reinterpret_cast<unsigned*>(&h2);
}
static __device__ inline short8 mk8(unsigned a, unsigned b, unsigned c, unsigned d) {
    union { short8 s; unsigned u[4]; } cv;
    cv.u[0] = a; cv.u[1] = b; cv.u[2] = c; cv.u[3] = d; return cv.s;
}

// K1: qkp (R6-phaseA proven body as standalone kernel). Grid (144,8), 9.2 KB LDS.
// W converted fp32->bf16 in-register (no wprep). Writes NPART=16 P partials.
__global__ __launch_bounds__(256) void qkp_kernel(const float* __restrict__ x,
        const float* __restrict__ Wqkv, float* __restrict__ Pparts) {
    __shared__ __align__(16) __hip_bfloat16 xs[64][72];   // 9.2 KB
    int t = threadIdx.x, w = t >> 6, l = t & 63;
    int l15 = l & 15, quad = l >> 4;
    int bx = blockIdx.x, b = blockIdx.y;
    int ck = bx >> 4, pt = bx & 15;
    int n0 = bx * 64;
    {
        int p = t & 63, cbase = (t >> 6) * 16;
        const float* xb = x + (size_t)b * CDIM * N_POS + n0 + p;
        #pragma unroll
        for (int j = 0; j < 16; j += 4) {
            float v0 = xb[(size_t)(cbase + j + 0) * N_POS];
            float v1 = xb[(size_t)(cbase + j + 1) * N_POS];
            float v2 = xb[(size_t)(cbase + j + 2) * N_POS];
            float v3 = xb[(size_t)(cbase + j + 3) * N_POS];
            uint2 u; u.x = pk2(v0, v1); u.y = pk2(v2, v3);
            *reinterpret_cast<uint2*>(&xs[p][cbase + j]) = u;
        }
    }
    __syncthreads();

    // qk MFMA: nt 0,1 = q-ch of head w, nt 2,3 = k-ch of head w; W cvt in-register
    f32x4 acc[4][4];
    #pragma unroll
    for (int mt = 0; mt < 4; ++mt)
        #pragma unroll
        for (int nt = 0; nt < 4; ++nt) acc[mt][nt] = (f32x4){0.f, 0.f, 0.f, 0.f};
    #pragma unroll
    for (int ks = 0; ks < 2; ++ks) {
        int k0 = ks * 32 + quad * 8;
        short8 av[4];
        #pragma unroll
        for (int mt = 0; mt < 4; ++mt)
            av[mt] = *reinterpret_cast<const short8*>(&xs[mt * 16 + l15][k0]);
        #pragma unroll
        for (int nt = 0; nt < 4; ++nt) {
            int row = (nt < 2) ? (w * 32 + nt * 16 + l15)
                               : (128 + w * 32 + (nt - 2) * 16 + l15);
            const float4* wr = (const float4*)(Wqkv + (size_t)row * 64 + k0);
            float4 wa = wr[0], wb = wr[1];
            short8 bwv = mk8(pk2(wa.x, wa.y), pk2(wa.z, wa.w),
                             pk2(wb.x, wb.y), pk2(wb.z, wb.w));
            #pragma unroll
            for (int mt = 0; mt < 4; ++mt)
                acc[mt][nt] = __builtin_amdgcn_mfma_f32_16x16x32_bf16(av[mt], bwv, acc[mt][nt], 0, 0, 0);
        }
    }

    // softmax/exp in-register, pack to bf16 pairs
    unsigned pk[4][4][2];
    #pragma unroll
    for (int mt = 0; mt < 4; ++mt) {
        f32x4 e2, e3;
        #pragma unroll
        for (int r = 0; r < 4; ++r) {
            float a2 = acc[mt][2][r], a3 = acc[mt][3][r];
            float m = fmaxf(a2, a3);
            m = fmaxf(m, __shfl_xor(m, 1));
            m = fmaxf(m, __shfl_xor(m, 2));
            m = fmaxf(m, __shfl_xor(m, 4));
            m = fmaxf(m, __shfl_xor(m, 8));
            float x2 = __expf(a2 - m), x3 = __expf(a3 - m);
            float s = x2 + x3;
            s += __shfl_xor(s, 1);
            s += __shfl_xor(s, 2);
            s += __shfl_xor(s, 4);
            s += __shfl_xor(s, 8);
            float is = 1.f / s;
            e2[r] = x2 * is; e3[r] = x3 * is;
        }
        pk[mt][2][0] = pk2(e2[0], e2[1]); pk[mt][2][1] = pk2(e2[2], e2[3]);
        pk[mt][3][0] = pk2(e3[0], e3[1]); pk[mt][3][1] = pk2(e3[2], e3[3]);
        pk[mt][0][0] = pk2(__expf(acc[mt][0][0]), __expf(acc[mt][0][1]));
        pk[mt][0][1] = pk2(__expf(acc[mt][0][2]), __expf(acc[mt][0][3]));
        pk[mt][1][0] = pk2(__expf(acc[mt][1][0]), __expf(acc[mt][1][1]));
        pk[mt][1][1] = pk2(__expf(acc[mt][1][2]), __expf(acc[mt][1][3]));
    }

    // shuffle-transpose to P-fragments + P MFMA
    f32x4 pac[2][2];
    pac[0][0] = (f32x4){0,0,0,0}; pac[0][1] = (f32x4){0,0,0,0};
    pac[1][0] = (f32x4){0,0,0,0}; pac[1][1] = (f32x4){0,0,0,0};
    int srcbase = ((quad & 1) * 2) * 16 + l15;
    bool hiHalf = (quad >= 2);
    #pragma unroll
    for (int ks = 0; ks < 2; ++ks) {
        unsigned fr[4][4];
        #pragma unroll
        for (int nt = 0; nt < 4; ++nt) {
            #pragma unroll
            for (int sl = 0; sl < 4; ++sl) {
                int src = srcbase + (sl >> 1) * 16;
                unsigned lo = __shfl(pk[2 * ks][nt][sl & 1], src);
                unsigned hi = __shfl(pk[2 * ks + 1][nt][sl & 1], src);
                fr[nt][sl] = hiHalf ? hi : lo;
            }
        }
        short8 A0 = mk8(fr[0][0], fr[0][1], fr[0][2], fr[0][3]);
        short8 A1 = mk8(fr[1][0], fr[1][1], fr[1][2], fr[1][3]);
        short8 B0 = mk8(fr[2][0], fr[2][1], fr[2][2], fr[2][3]);
        short8 B1 = mk8(fr[3][0], fr[3][1], fr[3][2], fr[3][3]);
        pac[0][0] = __builtin_amdgcn_mfma_f32_16x16x32_bf16(A0, B0, pac[0][0], 0, 0, 0);
        pac[0][1] = __builtin_amdgcn_mfma_f32_16x16x32_bf16(A0, B1, pac[0][1], 0, 0, 0);
        pac[1][0] = __builtin_amdgcn_mfma_f32_16x16x32_bf16(A1, B0, pac[1][0], 0, 0, 0);
        pac[1][1] = __builtin_amdgcn_mfma_f32_16x16x32_bf16(A1, B1, pac[1][1], 0, 0, 0);
    }
    float* Pp = Pparts + (((size_t)(b * NCHUNK + ck) * NPART + pt) * 4 + w) * 1024;
    #pragma unroll
    for (int tA = 0; tA < 2; ++tA)
        #pragma unroll
        for (int tB = 0; tB < 2; ++tB)
            #pragma unroll
            for (int r = 0; r < 4; ++r)
                Pp[(tA * 16 + quad * 4 + r) * 32 + tB * 16 + l15] = pac[tA][tB][r];
}

// K2: umat (R6-phaseB proven body). Grid (9,8,4).
__global__ __launch_bounds__(256) void umat_kernel(const float* __restrict__ Wout,
        const float* __restrict__ Wqkv, const float* __restrict__ Pparts,
        float* __restrict__ Mp) {
    __shared__ float Pl[32][32];
    __shared__ float iZ[32];
    __shared__ float Ul[64][33];
    __shared__ float Wvh[32][68];
    int ck = blockIdx.x, b = blockIdx.y, h = blockIdx.z;
    int t = threadIdx.x;
    {
        const float4* P0 = (const float4*)Pparts
            + ((size_t)(b * NCHUNK + ck) * NPART) * 1024 + h * 256 + t;
        float4 s = (float4){0.f, 0.f, 0.f, 0.f};
        #pragma unroll
        for (int pt = 0; pt < NPART; ++pt) {
            float4 a = P0[pt * 1024];
            s.x += a.x; s.y += a.y; s.z += a.z; s.w += a.w;
        }
        ((float4*)Pl)[t] = s;
    }
    {
        int e = t >> 3, cq = t & 7;
        const float4* wr = (const float4*)(Wqkv + (size_t)(256 + h * 32 + e) * 64 + cq * 8);
        float4 a0 = wr[0], a1 = wr[1];
        *reinterpret_cast<float4*>(&Wvh[e][cq * 8])     = a0;
        *reinterpret_cast<float4*>(&Wvh[e][cq * 8 + 4]) = a1;
    }
    __syncthreads();
    if (t < 32) {
        float s = 0.f;
        #pragma unroll
        for (int c = 0; c < 32; ++c) s += Pl[t][c];
        iZ[t] = 1.f / s;
    }
    __syncthreads();
    int o = t & 63, wv = t >> 6;
    float wz[32];
    {
        const float4* wr = (const float4*)(Wout + (size_t)o * 128 + h * 32);
        #pragma unroll
        for (int j = 0; j < 8; ++j) {
            float4 f = wr[j];
            wz[j*4+0] = f.x * iZ[j*4+0]; wz[j*4+1] = f.y * iZ[j*4+1];
            wz[j*4+2] = f.z * iZ[j*4+2]; wz[j*4+3] = f.w * iZ[j*4+3];
        }
    }
    float ua[8];
    #pragma unroll
    for (int j = 0; j < 8; ++j) ua[j] = 0.f;
    for (int d = 0; d < 32; ++d) {
        float wd = wz[d];
        #pragma unroll
        for (int j = 0; j < 8; ++j) ua[j] += wd * Pl[d][wv * 8 + j];
    }
    #pragma unroll
    for (int j = 0; j < 8; ++j) Ul[o][wv * 8 + j] = ua[j];
    __syncthreads();

    float macc[16];
    #pragma unroll
    for (int j = 0; j < 16; ++j) macc[j] = 0.f;
    for (int e = 0; e < 32; ++e) {
        float u = Ul[o][e];
        const float4* wvp = reinterpret_cast<const float4*>(&Wvh[e][wv * 16]);
        #pragma unroll
        for (int q = 0; q < 4; ++q) {
            float4 f = wvp[q];
            macc[q*4+0] += u * f.x; macc[q*4+1] += u * f.y;
            macc[q*4+2] += u * f.z; macc[q*4+3] += u * f.w;
        }
    }
    float* mp = Mp + (size_t)h * MP_SLICE + ((size_t)(b * NCHUNK + ck)) * 4096
              + (size_t)o * 64 + wv * 16;
    #pragma unroll
    for (int q = 0; q < 4; ++q) {
        float4 f; f.x = macc[q*4+0]; f.y = macc[q*4+1]; f.z = macc[q*4+2]; f.w = macc[q*4+3];
        reinterpret_cast<float4*>(mp)[q] = f;
    }
}

// K3: y = M.x + bias with IN-REGISTER GroupNorm: after stats atomics, per-batch
// counter + acquire-spin (all 576 blocks co-resident via cooperative launch),
// then normalize the accumulator tile and write fp32 out directly. No ybf, no gn.
__global__ __launch_bounds__(256) void y_kernel(const float* __restrict__ x,
        const float* __restrict__ Mp, const float* __restrict__ bout,
        const float* __restrict__ gamma, const float* __restrict__ beta,
        float* __restrict__ out, float* __restrict__ stats,
        unsigned* __restrict__ cntY) {
    __shared__ __align__(16) __hip_bfloat16 xs[128][72];   // 18.4 KB
    __shared__ __align__(16) __hip_bfloat16 Ml[64][72];    // 9.2 KB
    __shared__ float gsum[8], gsq[8];
    int bx = blockIdx.x, b = blockIdx.y;
    int ck = bx >> 3, n0 = bx * 128;
    int t = threadIdx.x, w = t >> 6, l = t & 63;
    int l15 = l & 15, quad = l >> 4;
    if (t < 8) { gsum[t] = 0.f; gsq[t] = 0.f; }
    {   // stage x tile: 2 threads per position, 32 channels each
        int p = t & 127, cbase = (t >> 7) * 32;
        const float* xb = x + (size_t)b * CDIM * N_POS + n0 + p;
        #pragma unroll
        for (int j = 0; j < 32; j += 4) {
            float v0 = xb[(size_t)(cbase + j + 0) * N_POS];
            float v1 = xb[(size_t)(cbase + j + 1) * N_POS];
            float v2 = xb[(size_t)(cbase + j + 2) * N_POS];
            float v3 = xb[(size_t)(cbase + j + 3) * N_POS];
            uint2 u; u.x = pk2(v0, v1); u.y = pk2(v2, v3);
            *reinterpret_cast<uint2*>(&xs[p][cbase + j]) = u;
        }
    }
    {   // stage M: sum 4 head-partials (L2-hot), cvt to bf16
        int o = t >> 2, cs = (t & 3) * 16;
        const float* mb = Mp + ((size_t)(b * NCHUNK + ck)) * 4096 + (size_t)o * 64 + cs;
        float m[16];
        #pragma unroll
        for (int q = 0; q < 4; ++q) {
            float4 f = reinterpret_cast<const float4*>(mb)[q];
            m[q*4+0] = f.x; m[q*4+1] = f.y; m[q*4+2] = f.z; m[q*4+3] = f.w;
        }
        #pragma unroll
        for (int h = 1; h < 4; ++h) {
            const float* mh = mb + h * MP_SLICE;
            #pragma unroll
            for (int q = 0; q < 4; ++q) {
                float4 f = reinterpret_cast<const float4*>(mh)[q];
                m[q*4+0] += f.x; m[q*4+1] += f.y; m[q*4+2] += f.z; m[q*4+3] += f.w;
            }
        }
        #pragma unroll
        for (int q = 0; q < 4; ++q) {
            uint2 u; u.x = pk2(m[q*4+0], m[q*4+1]); u.y = pk2(m[q*4+2], m[q*4+3]);
            *reinterpret_cast<uint2*>(&Ml[o][cs + q * 4]) = u;
        }
    }
    __syncthreads();

    int nw = w * 32;
    f32x4 acc[4][2];
    #pragma unroll
    for (int mt = 0; mt < 4; ++mt) { acc[mt][0] = (f32x4){0,0,0,0}; acc[mt][1] = (f32x4){0,0,0,0}; }
    #pragma unroll
    for (int ks = 0; ks < 2; ++ks) {
        int k0 = ks * 32 + quad * 8;
        short8 bf[2];
        #pragma unroll
        for (int nt = 0; nt < 2; ++nt)
            bf[nt] = *reinterpret_cast<const short8*>(&xs[nw + nt * 16 + l15][k0]);
        #pragma unroll
        for (int mt = 0; mt < 4; ++mt) {
            short8 af = *reinterpret_cast<const short8*>(&Ml[mt * 16 + l15][k0]);
            acc[mt][0] = __builtin_amdgcn_mfma_f32_16x16x32_bf16(af, bf[0], acc[mt][0], 0, 0, 0);
            acc[mt][1] = __builtin_amdgcn_mfma_f32_16x16x32_bf16(af, bf[1], acc[mt][1], 0, 0, 0);
        }
    }
    // bias in place + stats partials
    float gsl[4], gql[4];
    #pragma unroll
    for (int mt = 0; mt < 4; ++mt) { gsl[mt] = 0.f; gql[mt] = 0.f; }
    #pragma unroll
    for (int mt = 0; mt < 4; ++mt) {
        float4 bo = *reinterpret_cast<const float4*>(bout + mt * 16 + quad * 4);
        const float* bop = reinterpret_cast<const float*>(&bo);
        #pragma unroll
        for (int nt = 0; nt < 2; ++nt)
            #pragma unroll
            for (int r = 0; r < 4; ++r) {
                acc[mt][nt][r] += bop[r];
                gsl[mt] += acc[mt][nt][r];
                gql[mt] += acc[mt][nt][r] * acc[mt][nt][r];
            }
    }
    #pragma unroll
    for (int off = 16; off >= 1; off >>= 1) {
        #pragma unroll
        for (int mt = 0; mt < 4; ++mt) {
            gsl[mt] += __shfl_xor(gsl[mt], off, 64);
            gql[mt] += __shfl_xor(gql[mt], off, 64);
        }
    }
    if (l == 0 || l == 32) {
        int qh = quad >> 1;
        #pragma unroll
        for (int mt = 0; mt < 4; ++mt) {
            atomicAdd(&gsum[2 * mt + qh], gsl[mt]);
            atomicAdd(&gsq[2 * mt + qh], gql[mt]);
        }
    }
    __syncthreads();
    if (t < 8) {
        atomicAdd(&stats[(b * 8 + t) * 2],     gsum[t]);
        atomicAdd(&stats[(b * 8 + t) * 2 + 1], gsq[t]);
    }
    __threadfence();        // release: prior stats atomics complete & visible
    __syncthreads();
    if (t == 0) {
        atomicAdd(&cntY[b], 1u);
        while (__hip_atomic_load(&cntY[b], __ATOMIC_ACQUIRE,
                                 __HIP_MEMORY_SCOPE_AGENT) < 72u)
            __builtin_amdgcn_s_sleep(4);
    }
    __syncthreads();

    // normalize in-register, write fp32 out
    const float invN = 1.f / (8.f * N_POS);
    float* ob = out + (size_t)b * CDIM * N_POS;
    int nbase = n0 + nw;
    int qh = quad >> 1;
    #pragma unroll
    for (int mt = 0; mt < 4; ++mt) {
        int g = 2 * mt + qh;
        float s = __hip_atomic_load(&stats[(b * 8 + g) * 2], __ATOMIC_RELAXED,
                                    __HIP_MEMORY_SCOPE_AGENT);
        float q = __hip_atomic_load(&stats[(b * 8 + g) * 2 + 1], __ATOMIC_RELAXED,
                                    __HIP_MEMORY_SCOPE_AGENT);
        float mean = s * invN;
        float var = q * invN - mean * mean;
        float sc = rsqrtf(var + EPS);
        #pragma unroll
        for (int r = 0; r < 4; ++r) {
            int o = mt * 16 + quad * 4 + r;
            float gg = gamma[o] * sc;
            float bb = beta[o] - mean * gg;
            #pragma unroll
            for (int nt = 0; nt < 2; ++nt) {
                int n = nbase + nt * 16 + l15;
                ob[(size_t)o * N_POS + n] = acc[mt][nt][r] * gg + bb;
            }
        }
    }
}

extern "C" void kernel_launch(void* const* d_in, const int* in_sizes, int n_in,
                              void* d_out, int out_size, void* d_ws, size_t ws_size,
                              hipStream_t stream) {
    const float* x     = (const float*)d_in[0];
    const float* Wqkv  = (const float*)d_in[1];
    const float* Wout  = (const float*)d_in[2];
    const float* bout  = (const float*)d_in[3];
    const float* gamma = (const float*)d_in[4];
    const float* beta  = (const float*)d_in[5];
    float* out = (float*)d_out;

    float* stats   = (float*)d_ws;                 // 128 f
    unsigned* cntY = (unsigned*)(stats + 128);     // 8 u32
    float* Pparts  = (float*)((char*)d_ws + 1024);
    float* Mp      = Pparts + PPARTS_TOT;

    hipMemsetAsync(d_ws, 0, 1024, stream);         // zero stats + counters
    qkp_kernel<<<dim3(144, BATCH), 256, 0, stream>>>(x, Wqkv, Pparts);
    umat_kernel<<<dim3(NCHUNK, BATCH, HEADS), 256, 0, stream>>>(Wout, Wqkv, Pparts, Mp);

    void* args[] = { (void*)&x, (void*)&Mp, (void*)&bout, (void*)&gamma,
                     (void*)&beta, (void*)&out, (void*)&stats, (void*)&cntY };
    if (hipLaunchCooperativeKernel((const void*)y_kernel, dim3(72, BATCH),
                                   dim3(256), args, 0, stream) != hipSuccess) {
        // fallback: plain launch — 576 blocks all fit co-resident (27.7 KB LDS -> 5/CU)
        y_kernel<<<dim3(72, BATCH), 256, 0, stream>>>(x, Mp, bout, gamma, beta,
                                                      out, stats, cntY);
    }
}

// Round 8
// 146.338 us; speedup vs baseline: 2.3440x; 1.6317x over previous
//
#include <hip/hip_runtime.h>
#include <hip/hip_bf16.h>

#define N_POS 9216
#define NCHUNK 9
#define BATCH 8
#define CDIM 64
#define HEADS 4
#define EPS 1e-5f

// ws layout: stats f32[128] | pad to 1024B | Pparts fp32 | Mbf bf16[72][64][64] | ybf bf16
#define NPART 16
#define PPARTS_TOT ((size_t)BATCH * NCHUNK * NPART * 4096)
#define MBF_ELEMS ((size_t)BATCH * NCHUNK * 4096)

typedef __attribute__((ext_vector_type(8))) short short8;
typedef __attribute__((ext_vector_type(4))) float f32x4;

static __device__ inline unsigned pk2(float a, float b) {
    __hip_bfloat162 h2(__float2bfloat16(a), __float2bfloat16(b));
    return *reinterpret_cast<unsigned*>(&h2);
}
static __device__ inline float bf2f(short s) {
    union { unsigned u; float f; } c; c.u = ((unsigned)(unsigned short)s) << 16; return c.f;
}
static __device__ inline short8 mk8(unsigned a, unsigned b, unsigned c, unsigned d) {
    union { short8 s; unsigned u[4]; } cv;
    cv.u[0] = a; cv.u[1] = b; cv.u[2] = c; cv.u[3] = d; return cv.s;
}

// K1: qkp (R7-proven body). Grid (144,8), 9.2 KB LDS, W cvt fp32->bf16 in-register.
__global__ __launch_bounds__(256) void qkp_kernel(const float* __restrict__ x,
        const float* __restrict__ Wqkv, float* __restrict__ Pparts) {
    __shared__ __align__(16) __hip_bfloat16 xs[64][72];   // 9.2 KB
    int t = threadIdx.x, w = t >> 6, l = t & 63;
    int l15 = l & 15, quad = l >> 4;
    int bx = blockIdx.x, b = blockIdx.y;
    int ck = bx >> 4, pt = bx & 15;
    int n0 = bx * 64;
    {
        int p = t & 63, cbase = (t >> 6) * 16;
        const float* xb = x + (size_t)b * CDIM * N_POS + n0 + p;
        #pragma unroll
        for (int j = 0; j < 16; j += 4) {
            float v0 = xb[(size_t)(cbase + j + 0) * N_POS];
            float v1 = xb[(size_t)(cbase + j + 1) * N_POS];
            float v2 = xb[(size_t)(cbase + j + 2) * N_POS];
            float v3 = xb[(size_t)(cbase + j + 3) * N_POS];
            uint2 u; u.x = pk2(v0, v1); u.y = pk2(v2, v3);
            *reinterpret_cast<uint2*>(&xs[p][cbase + j]) = u;
        }
    }
    __syncthreads();

    f32x4 acc[4][4];
    #pragma unroll
    for (int mt = 0; mt < 4; ++mt)
        #pragma unroll
        for (int nt = 0; nt < 4; ++nt) acc[mt][nt] = (f32x4){0.f, 0.f, 0.f, 0.f};
    #pragma unroll
    for (int ks = 0; ks < 2; ++ks) {
        int k0 = ks * 32 + quad * 8;
        short8 av[4];
        #pragma unroll
        for (int mt = 0; mt < 4; ++mt)
            av[mt] = *reinterpret_cast<const short8*>(&xs[mt * 16 + l15][k0]);
        #pragma unroll
        for (int nt = 0; nt < 4; ++nt) {
            int row = (nt < 2) ? (w * 32 + nt * 16 + l15)
                               : (128 + w * 32 + (nt - 2) * 16 + l15);
            const float4* wr = (const float4*)(Wqkv + (size_t)row * 64 + k0);
            float4 wa = wr[0], wb = wr[1];
            short8 bwv = mk8(pk2(wa.x, wa.y), pk2(wa.z, wa.w),
                             pk2(wb.x, wb.y), pk2(wb.z, wb.w));
            #pragma unroll
            for (int mt = 0; mt < 4; ++mt)
                acc[mt][nt] = __builtin_amdgcn_mfma_f32_16x16x32_bf16(av[mt], bwv, acc[mt][nt], 0, 0, 0);
        }
    }

    unsigned pk[4][4][2];
    #pragma unroll
    for (int mt = 0; mt < 4; ++mt) {
        f32x4 e2, e3;
        #pragma unroll
        for (int r = 0; r < 4; ++r) {
            float a2 = acc[mt][2][r], a3 = acc[mt][3][r];
            float m = fmaxf(a2, a3);
            m = fmaxf(m, __shfl_xor(m, 1));
            m = fmaxf(m, __shfl_xor(m, 2));
            m = fmaxf(m, __shfl_xor(m, 4));
            m = fmaxf(m, __shfl_xor(m, 8));
            float x2 = __expf(a2 - m), x3 = __expf(a3 - m);
            float s = x2 + x3;
            s += __shfl_xor(s, 1);
            s += __shfl_xor(s, 2);
            s += __shfl_xor(s, 4);
            s += __shfl_xor(s, 8);
            float is = 1.f / s;
            e2[r] = x2 * is; e3[r] = x3 * is;
        }
        pk[mt][2][0] = pk2(e2[0], e2[1]); pk[mt][2][1] = pk2(e2[2], e2[3]);
        pk[mt][3][0] = pk2(e3[0], e3[1]); pk[mt][3][1] = pk2(e3[2], e3[3]);
        pk[mt][0][0] = pk2(__expf(acc[mt][0][0]), __expf(acc[mt][0][1]));
        pk[mt][0][1] = pk2(__expf(acc[mt][0][2]), __expf(acc[mt][0][3]));
        pk[mt][1][0] = pk2(__expf(acc[mt][1][0]), __expf(acc[mt][1][1]));
        pk[mt][1][1] = pk2(__expf(acc[mt][1][2]), __expf(acc[mt][1][3]));
    }

    f32x4 pac[2][2];
    pac[0][0] = (f32x4){0,0,0,0}; pac[0][1] = (f32x4){0,0,0,0};
    pac[1][0] = (f32x4){0,0,0,0}; pac[1][1] = (f32x4){0,0,0,0};
    int srcbase = ((quad & 1) * 2) * 16 + l15;
    bool hiHalf = (quad >= 2);
    #pragma unroll
    for (int ks = 0; ks < 2; ++ks) {
        unsigned fr[4][4];
        #pragma unroll
        for (int nt = 0; nt < 4; ++nt) {
            #pragma unroll
            for (int sl = 0; sl < 4; ++sl) {
                int src = srcbase + (sl >> 1) * 16;
                unsigned lo = __shfl(pk[2 * ks][nt][sl & 1], src);
                unsigned hi = __shfl(pk[2 * ks + 1][nt][sl & 1], src);
                fr[nt][sl] = hiHalf ? hi : lo;
            }
        }
        short8 A0 = mk8(fr[0][0], fr[0][1], fr[0][2], fr[0][3]);
        short8 A1 = mk8(fr[1][0], fr[1][1], fr[1][2], fr[1][3]);
        short8 B0 = mk8(fr[2][0], fr[2][1], fr[2][2], fr[2][3]);
        short8 B1 = mk8(fr[3][0], fr[3][1], fr[3][2], fr[3][3]);
        pac[0][0] = __builtin_amdgcn_mfma_f32_16x16x32_bf16(A0, B0, pac[0][0], 0, 0, 0);
        pac[0][1] = __builtin_amdgcn_mfma_f32_16x16x32_bf16(A0, B1, pac[0][1], 0, 0, 0);
        pac[1][0] = __builtin_amdgcn_mfma_f32_16x16x32_bf16(A1, B0, pac[1][0], 0, 0, 0);
        pac[1][1] = __builtin_amdgcn_mfma_f32_16x16x32_bf16(A1, B1, pac[1][1], 0, 0, 0);
    }
    float* Pp = Pparts + (((size_t)(b * NCHUNK + ck) * NPART + pt) * 4 + w) * 1024;
    #pragma unroll
    for (int tA = 0; tA < 2; ++tA)
        #pragma unroll
        for (int tB = 0; tB < 2; ++tB)
            #pragma unroll
            for (int r = 0; r < 4; ++r)
                Pp[(tA * 16 + quad * 4 + r) * 32 + tB * 16 + l15] = pac[tA][tB][r];
}

// K2: umat, grid (9,8). Loops the 4 heads, accumulates M = sum_h U'_h.Wv_h in
// registers, writes the SUMMED M as bf16 (8 KB per (b,ck)) — y reads it L2-hot.
__global__ __launch_bounds__(256) void umat_kernel(const float* __restrict__ Wout,
        const float* __restrict__ Wqkv, const float* __restrict__ Pparts,
        __hip_bfloat16* __restrict__ Mbf) {
    __shared__ float Pl[32][32];
    __shared__ float iZ[32];
    __shared__ float Ul[64][33];
    __shared__ float Wvh[32][68];
    int ck = blockIdx.x, b = blockIdx.y;
    int t = threadIdx.x;
    int o = t & 63, wv = t >> 6;
    float macc[16];
    #pragma unroll
    for (int j = 0; j < 16; ++j) macc[j] = 0.f;
    for (int h = 0; h < 4; ++h) {
        __syncthreads();   // protect Pl/Wvh/Ul reuse across head iterations
        {
            const float4* P0 = (const float4*)Pparts
                + ((size_t)(b * NCHUNK + ck) * NPART) * 1024 + h * 256 + t;
            float4 s = (float4){0.f, 0.f, 0.f, 0.f};
            #pragma unroll
            for (int pt = 0; pt < NPART; ++pt) {
                float4 a = P0[pt * 1024];
                s.x += a.x; s.y += a.y; s.z += a.z; s.w += a.w;
            }
            ((float4*)Pl)[t] = s;
        }
        {
            int e = t >> 3, cq = t & 7;
            const float4* wr = (const float4*)(Wqkv + (size_t)(256 + h * 32 + e) * 64 + cq * 8);
            float4 a0 = wr[0], a1 = wr[1];
            *reinterpret_cast<float4*>(&Wvh[e][cq * 8])     = a0;
            *reinterpret_cast<float4*>(&Wvh[e][cq * 8 + 4]) = a1;
        }
        __syncthreads();
        if (t < 32) {
            float s = 0.f;
            #pragma unroll
            for (int c = 0; c < 32; ++c) s += Pl[t][c];
            iZ[t] = 1.f / s;
        }
        __syncthreads();
        float wz[32];
        {
            const float4* wr = (const float4*)(Wout + (size_t)o * 128 + h * 32);
            #pragma unroll
            for (int j = 0; j < 8; ++j) {
                float4 f = wr[j];
                wz[j*4+0] = f.x * iZ[j*4+0]; wz[j*4+1] = f.y * iZ[j*4+1];
                wz[j*4+2] = f.z * iZ[j*4+2]; wz[j*4+3] = f.w * iZ[j*4+3];
            }
        }
        float ua[8];
        #pragma unroll
        for (int j = 0; j < 8; ++j) ua[j] = 0.f;
        for (int d = 0; d < 32; ++d) {
            float wd = wz[d];
            #pragma unroll
            for (int j = 0; j < 8; ++j) ua[j] += wd * Pl[d][wv * 8 + j];
        }
        #pragma unroll
        for (int j = 0; j < 8; ++j) Ul[o][wv * 8 + j] = ua[j];
        __syncthreads();
        for (int e = 0; e < 32; ++e) {
            float u = Ul[o][e];
            const float4* wvp = reinterpret_cast<const float4*>(&Wvh[e][wv * 16]);
            #pragma unroll
            for (int q = 0; q < 4; ++q) {
                float4 f = wvp[q];
                macc[q*4+0] += u * f.x; macc[q*4+1] += u * f.y;
                macc[q*4+2] += u * f.z; macc[q*4+3] += u * f.w;
            }
        }
    }
    __hip_bfloat16* mp = Mbf + (size_t)(b * NCHUNK + ck) * 4096 + (size_t)o * 64 + wv * 16;
    #pragma unroll
    for (int q = 0; q < 4; ++q) {
        uint2 u; u.x = pk2(macc[q*4+0], macc[q*4+1]); u.y = pk2(macc[q*4+2], macc[q*4+3]);
        reinterpret_cast<uint2*>(mp)[q] = u;
    }
}

// K3: y = M.x + bias + GN stats. Grid (144,8): 64-pos tiles -> 1152 blocks
// (4.5/CU, occupancy cap 56% vs 23% before). M frags direct from global bf16
// (L2-hot, issued before the barrier); only x staged in LDS (9.2 KB).
__global__ __launch_bounds__(256) void y_kernel(const float* __restrict__ x,
        const __hip_bfloat16* __restrict__ Mbf, const float* __restrict__ bout,
        __hip_bfloat16* __restrict__ ybf, float* __restrict__ stats) {
    __shared__ __align__(16) __hip_bfloat16 xs[64][72];   // 9.2 KB
    __shared__ float gsum[8], gsq[8];
    int bx = blockIdx.x, b = blockIdx.y;
    int ck = bx >> 4, n0 = bx * 64;
    int t = threadIdx.x, w = t >> 6, l = t & 63;
    int l15 = l & 15, quad = l >> 4;
    if (t < 8) { gsum[t] = 0.f; gsq[t] = 0.f; }

    // M fragments from global bf16 (8 KB per (b,ck), shared by 16 blocks -> L2)
    short8 af[4][2];
    {
        const __hip_bfloat16* Mb = Mbf + (size_t)(b * NCHUNK + ck) * 4096;
        #pragma unroll
        for (int mt = 0; mt < 4; ++mt)
            #pragma unroll
            for (int ks = 0; ks < 2; ++ks)
                af[mt][ks] = *reinterpret_cast<const short8*>(
                    Mb + (size_t)(mt * 16 + l15) * 64 + ks * 32 + quad * 8);
    }
    // stage x tile (coalesced)
    {
        int p = t & 63, cbase = (t >> 6) * 16;
        const float* xb = x + (size_t)b * CDIM * N_POS + n0 + p;
        #pragma unroll
        for (int j = 0; j < 16; j += 4) {
            float v0 = xb[(size_t)(cbase + j + 0) * N_POS];
            float v1 = xb[(size_t)(cbase + j + 1) * N_POS];
            float v2 = xb[(size_t)(cbase + j + 2) * N_POS];
            float v3 = xb[(size_t)(cbase + j + 3) * N_POS];
            uint2 u; u.x = pk2(v0, v1); u.y = pk2(v2, v3);
            *reinterpret_cast<uint2*>(&xs[p][cbase + j]) = u;
        }
    }
    __syncthreads();

    // y MFMA: wave w owns positions n0+w*16..+16; acc[mt] = 64 out-ch x 16 pos
    f32x4 acc[4];
    #pragma unroll
    for (int mt = 0; mt < 4; ++mt) acc[mt] = (f32x4){0.f, 0.f, 0.f, 0.f};
    #pragma unroll
    for (int ks = 0; ks < 2; ++ks) {
        int k0 = ks * 32 + quad * 8;
        short8 bf = *reinterpret_cast<const short8*>(&xs[w * 16 + l15][k0]);
        #pragma unroll
        for (int mt = 0; mt < 4; ++mt)
            acc[mt] = __builtin_amdgcn_mfma_f32_16x16x32_bf16(af[mt][ks], bf, acc[mt], 0, 0, 0);
    }
    // bias + stats partials
    float gsl[4], gql[4];
    #pragma unroll
    for (int mt = 0; mt < 4; ++mt) { gsl[mt] = 0.f; gql[mt] = 0.f; }
    #pragma unroll
    for (int mt = 0; mt < 4; ++mt) {
        float4 bo = *reinterpret_cast<const float4*>(bout + mt * 16 + quad * 4);
        const float* bop = reinterpret_cast<const float*>(&bo);
        #pragma unroll
        for (int r = 0; r < 4; ++r) {
            acc[mt][r] += bop[r];
            gsl[mt] += acc[mt][r];
            gql[mt] += acc[mt][r] * acc[mt][r];
        }
    }
    #pragma unroll
    for (int off = 16; off >= 1; off >>= 1) {
        #pragma unroll
        for (int mt = 0; mt < 4; ++mt) {
            gsl[mt] += __shfl_xor(gsl[mt], off, 64);
            gql[mt] += __shfl_xor(gql[mt], off, 64);
        }
    }
    if (l == 0 || l == 32) {
        int qh = quad >> 1;
        #pragma unroll
        for (int mt = 0; mt < 4; ++mt) {
            atomicAdd(&gsum[2 * mt + qh], gsl[mt]);
            atomicAdd(&gsq[2 * mt + qh], gql[mt]);
        }
    }
    // write pre-norm y as bf16
    __hip_bfloat16* yb = ybf + (size_t)b * CDIM * N_POS;
    int n = n0 + w * 16 + l15;
    #pragma unroll
    for (int mt = 0; mt < 4; ++mt)
        #pragma unroll
        for (int r = 0; r < 4; ++r) {
            int o = mt * 16 + quad * 4 + r;
            yb[(size_t)o * N_POS + n] = __float2bfloat16(acc[mt][r]);
        }
    __syncthreads();
    if (t < 8) {
        atomicAdd(&stats[(b * 8 + t) * 2],     gsum[t]);
        atomicAdd(&stats[(b * 8 + t) * 2 + 1], gsq[t]);
    }
}

// K4: GN normalize (R0-proven). Grid (9,512).
__global__ __launch_bounds__(256) void gn_kernel(const __hip_bfloat16* __restrict__ ybf,
        float* __restrict__ out, const float* __restrict__ stats,
        const float* __restrict__ gamma, const float* __restrict__ beta) {
    int bc = blockIdx.y;            // 512 = b*64 + c
    int c = bc & 63, b = bc >> 6;
    int g = c >> 3;
    float s = stats[(b * 8 + g) * 2], q = stats[(b * 8 + g) * 2 + 1];
    const float invN = 1.f / (8.f * N_POS);
    float mean = s * invN;
    float var = q * invN - mean * mean;
    float sc = rsqrtf(var + EPS);
    float ga = gamma[c] * sc;
    float be = beta[c] - mean * sc * gamma[c];
    size_t base = ((size_t)b * CDIM + c) * N_POS + (size_t)(blockIdx.x * 256 + threadIdx.x) * 4;
    uint2 u = *reinterpret_cast<const uint2*>(ybf + base);
    float4 v;
    v.x = bf2f((short)(u.x & 0xffff)); v.y = bf2f((short)(u.x >> 16));
    v.z = bf2f((short)(u.y & 0xffff)); v.w = bf2f((short)(u.y >> 16));
    v.x = v.x * ga + be; v.y = v.y * ga + be; v.z = v.z * ga + be; v.w = v.w * ga + be;
    *reinterpret_cast<float4*>(out + base) = v;
}

extern "C" void kernel_launch(void* const* d_in, const int* in_sizes, int n_in,
                              void* d_out, int out_size, void* d_ws, size_t ws_size,
                              hipStream_t stream) {
    const float* x     = (const float*)d_in[0];
    const float* Wqkv  = (const float*)d_in[1];
    const float* Wout  = (const float*)d_in[2];
    const float* bout  = (const float*)d_in[3];
    const float* gamma = (const float*)d_in[4];
    const float* beta  = (const float*)d_in[5];
    float* out = (float*)d_out;

    float* stats  = (float*)d_ws;                       // 128 f
    float* Pparts = (float*)((char*)d_ws + 1024);
    __hip_bfloat16* Mbf = (__hip_bfloat16*)(Pparts + PPARTS_TOT);
    __hip_bfloat16* ybf = Mbf + MBF_ELEMS;

    hipMemsetAsync(d_ws, 0, 512, stream);               // zero stats
    qkp_kernel<<<dim3(144, BATCH), 256, 0, stream>>>(x, Wqkv, Pparts);
    umat_kernel<<<dim3(NCHUNK, BATCH), 256, 0, stream>>>(Wout, Wqkv, Pparts, Mbf);
    y_kernel<<<dim3(144, BATCH), 256, 0, stream>>>(x, Mbf, bout, ybf, stats);
    gn_kernel<<<dim3(9, 512), 256, 0, stream>>>(ybf, out, stats, gamma, beta);
}